// Round 2
// baseline (324.659 us; speedup 1.0000x reference)
//
#include <hip/hip_runtime.h>

// BSScanThru: out = brev8( (brev8(a) + brev8(b) + carry-chain) mod 256 ) & ~b
// Carry chain runs across the entire 2^26-element array (carry-lookahead scan).
//
// Inputs: int32 arrays (values 0..255). Output: int32 per element (the harness
// reads d_out as int32 for integer-dtype references — round-1 evidence:
// float-bit-pattern-sized absmax error).
//
// 3-pass structure:
//   pass1: per-1024-elem tile (g,p) aggregate -> ws[0..NB)
//   pass2: single-block exclusive scan of NB aggregates -> per-tile carry bit ws[NB..2NB)
//   pass3: recompute, apply carries, write int32 output.

#define BLK 256
#define EPT 4
#define TILE (BLK * EPT)   // 1024 elements per block

// (g,p) packed in 2 bits: bit0 = g (generate), bit1 = p (propagate).
// Identity element: g=0, p=1  -> 2u.
__device__ __forceinline__ unsigned gp_combine(unsigned l, unsigned r) {
    unsigned g = (r & 1u) | ((r >> 1) & l & 1u);   // gr | (pr & gl)
    unsigned p = (l >> 1) & (r >> 1) & 1u;         // pl & pr
    return g | (p << 1);
}

__device__ __forceinline__ unsigned brev8(unsigned x) {
    return __brev(x) >> 24;   // reverse 8 bits of a byte value
}

__global__ __launch_bounds__(BLK) void bss_pass1(const int* __restrict__ a,
                                                 const int* __restrict__ b,
                                                 unsigned char* __restrict__ agg) {
    const int base = blockIdx.x * TILE + threadIdx.x * EPT;
    int4 av = *reinterpret_cast<const int4*>(a + base);
    int4 bv = *reinterpret_cast<const int4*>(b + base);
    const int* ae = reinterpret_cast<const int*>(&av);
    const int* be = reinterpret_cast<const int*>(&bv);

    unsigned t = 2u;  // identity
#pragma unroll
    for (int k = 0; k < EPT; ++k) {
        unsigned s = brev8((unsigned)ae[k] & 0xFFu) + brev8((unsigned)be[k] & 0xFFu);
        unsigned c = s & 0xFFu;
        unsigned gp = (s >> 8) | ((unsigned)(c == 0xFFu) << 1);
        t = gp_combine(t, gp);
    }

    __shared__ unsigned sh[BLK];
    sh[threadIdx.x] = t;
    __syncthreads();
    // order-preserving tree reduce (left operand is the earlier segment)
    for (int off = 1; off < BLK; off <<= 1) {
        unsigned v = 0;
        bool act = ((threadIdx.x & (2 * off - 1)) == 0);
        if (act) v = gp_combine(sh[threadIdx.x], sh[threadIdx.x + off]);
        __syncthreads();
        if (act) sh[threadIdx.x] = v;
        __syncthreads();
    }
    if (threadIdx.x == 0) agg[blockIdx.x] = (unsigned char)sh[0];
}

#define P2T 1024
__global__ __launch_bounds__(P2T) void bss_pass2(const unsigned char* __restrict__ agg,
                                                 unsigned char* __restrict__ carry,
                                                 int nb) {
    __shared__ unsigned sh[P2T];
    const int t = threadIdx.x;
    const int per = nb / P2T;  // nb = 65536 -> 64

    unsigned acc = 2u;
    for (int k = 0; k < per; ++k)
        acc = gp_combine(acc, (unsigned)agg[t * per + k]);
    sh[t] = acc;
    __syncthreads();

    // Hillis-Steele inclusive scan over thread aggregates
    for (int off = 1; off < P2T; off <<= 1) {
        unsigned v = sh[t];
        if (t >= off) v = gp_combine(sh[t - off], v);
        __syncthreads();
        sh[t] = v;
        __syncthreads();
    }

    unsigned run = (t == 0) ? 2u : sh[t - 1];  // exclusive prefix
    for (int k = 0; k < per; ++k) {
        carry[t * per + k] = (unsigned char)(run & 1u);  // carry into tile t*per+k
        run = gp_combine(run, (unsigned)agg[t * per + k]);
    }
}

__global__ __launch_bounds__(BLK) void bss_pass3(const int* __restrict__ a,
                                                 const int* __restrict__ b,
                                                 const unsigned char* __restrict__ carry,
                                                 int* __restrict__ out) {
    const int base = blockIdx.x * TILE + threadIdx.x * EPT;
    int4 av = *reinterpret_cast<const int4*>(a + base);
    int4 bv = *reinterpret_cast<const int4*>(b + base);
    const int* ae = reinterpret_cast<const int*>(&av);
    const int* be = reinterpret_cast<const int*>(&bv);

    unsigned c[EPT], gp[EPT];
    unsigned t = 2u;
#pragma unroll
    for (int k = 0; k < EPT; ++k) {
        unsigned s = brev8((unsigned)ae[k] & 0xFFu) + brev8((unsigned)be[k] & 0xFFu);
        c[k] = s & 0xFFu;
        gp[k] = (s >> 8) | ((unsigned)(c[k] == 0xFFu) << 1);
        t = gp_combine(t, gp[k]);
    }

    __shared__ unsigned sh[BLK];
    sh[threadIdx.x] = t;
    __syncthreads();
    for (int off = 1; off < BLK; off <<= 1) {
        unsigned v = sh[threadIdx.x];
        if (threadIdx.x >= off) v = gp_combine(sh[threadIdx.x - off], v);
        __syncthreads();
        sh[threadIdx.x] = v;
        __syncthreads();
    }
    unsigned ex = (threadIdx.x == 0) ? 2u : sh[threadIdx.x - 1];

    unsigned cb = (unsigned)carry[blockIdx.x] & 1u;
    // carry into this thread's first element: Eg | (Ep & cb)
    unsigned cin = (ex & 1u) | (((ex >> 1) & 1u) & cb);

    int4 o;
    int* of = reinterpret_cast<int*>(&o);
#pragma unroll
    for (int k = 0; k < EPT; ++k) {
        unsigned bev = (unsigned)be[k] & 0xFFu;
        unsigned res = (c[k] + cin) & 0xFFu;
        unsigned ob = brev8(res) & (~bev & 0xFFu);
        of[k] = (int)ob;
        // ripple: carry into next element = g | (p & cin)
        cin = (gp[k] & 1u) | (((gp[k] >> 1) & 1u) & cin);
    }
    *reinterpret_cast<int4*>(out + base) = o;
}

extern "C" void kernel_launch(void* const* d_in, const int* in_sizes, int n_in,
                              void* d_out, int out_size, void* d_ws, size_t ws_size,
                              hipStream_t stream) {
    const int* a = (const int*)d_in[0];
    const int* b = (const int*)d_in[1];
    int* out = (int*)d_out;
    const int n = in_sizes[0];      // 67108864
    const int nb = n / TILE;        // 65536

    unsigned char* agg = (unsigned char*)d_ws;
    unsigned char* carry = agg + nb;

    bss_pass1<<<nb, BLK, 0, stream>>>(a, b, agg);
    bss_pass2<<<1, P2T, 0, stream>>>(agg, carry, nb);
    bss_pass3<<<nb, BLK, 0, stream>>>(a, b, carry, out);
}